// Round 6
// baseline (123.108 us; speedup 1.0000x reference)
//
#include <hip/hip_runtime.h>
#include <hip/hip_cooperative_groups.h>

namespace cg = cooperative_groups;

#define NR 1024
#define DX 256
#define HX 512

typedef __bf16 bf16x8 __attribute__((ext_vector_type(8)));
typedef float  f32x4  __attribute__((ext_vector_type(4)));

// ---- ws byte offsets (~7.3 MB used)
#define B_CM    0u         // f32 [2][16][256] raw column sums per 64-row stripe
#define B_PART  32768u     // f32 [256] block partials
#define B_CTR   36864u     // u32 completion counter (reset each call in phase 0)
#define B_HBH   65536u     // ushort [1024][256]  H hi
#define B_HBL   589824u    // H lo
#define B_PBH   1114112u   // P hi
#define B_PBL   1638400u   // P lo
#define B_WT1   2162688u   // ushort [512][256]  W1^T bf16
#define B_WT1G  2424832u   // ushort [512][512]  W1g^T
#define B_WT2   2949120u   // ushort [256][512]  W2^T
#define B_WT2G  3211264u   // ushort [256][512]  W2g^T
#define B_H1H   3473408u   // ushort [1024][512] Hid1 hi
#define B_H1L   4521984u   // Hid1 lo
#define B_HGH   5570560u   // Hidg hi
#define B_HGL   6619136u   // Hidg lo

#define GLDS16(gp, lp) __builtin_amdgcn_global_load_lds(                     \
    (const __attribute__((address_space(1))) void*)(gp),                     \
    (__attribute__((address_space(3))) void*)(lp), 16, 0, 0)

__device__ __forceinline__ unsigned short bf16rne(float x) {
    unsigned int u = __float_as_uint(x);
    u = u + 0x7FFFu + ((u >> 16) & 1u);
    return (unsigned short)(u >> 16);
}
__device__ __forceinline__ float bf16f(unsigned short h) {
    return __uint_as_float(((unsigned int)h) << 16);
}

// LDS phase union: prep-transpose tile / GEMM buffers / final double reduce
union SMem {
    struct {
        unsigned short Ah[2][4096], Al[2][4096], W[2][4096];  // 48 KB
        float red[256];
    } g;
    unsigned short T[64][72];
    double dred[256];
};

// ---------------------------------------------------------------------------
// Stage a 64x64-bf16 tile (row stride ld elems) into LDS [64][64] with 16B-slot
// swizzle slot' = slot ^ (row&7), applied by permuting the per-lane GLOBAL
// source (global_load_lds writes linearly, rule 21).
__device__ __forceinline__ void stage_bf16(const unsigned short* src, int r0, int c0,
                                           int ld, unsigned short* lds, int wv, int ln)
{
    const int gsl = (ln & 7) ^ ((ln >> 3) & 7);
    #pragma unroll
    for (int i = 0; i < 2; ++i) {
        const int ins = wv * 2 + i;               // 1 KB chunk id 0..7 (8 rows each)
        const unsigned short* gp =
            src + (size_t)(r0 + ins * 8 + (ln >> 3)) * ld + c0 + gsl * 8;
        GLDS16(gp, lds + ins * 512);
    }
}

// Fragment read: 8 consecutive bf16 of (row, k=kc+8*(ln>>4)..+8), swizzled slot.
__device__ __forceinline__ uint4 ldsfrag(const unsigned short* lds, int row, int kc, int ln)
{
    const int slot = ((kc >> 3) + (ln >> 4)) ^ (row & 7);
    return *(const uint4*)((const char*)lds + row * 128 + slot * 16);
}

#define MFMA(a, b, c) __builtin_amdgcn_mfma_f32_16x16x32_bf16(                \
    __builtin_bit_cast(bf16x8, a), __builtin_bit_cast(bf16x8, b), c, 0, 0, 0)

// ---------------------------------------------------------------------------
__global__ __launch_bounds__(256) void fused_kernel(
    const float* __restrict__ H, const float* __restrict__ P, const float* __restrict__ G,
    const float* __restrict__ W1, const float* __restrict__ b1,
    const float* __restrict__ W1g, const float* __restrict__ b1g,
    const float* __restrict__ W2, const float* __restrict__ W2g,
    char* __restrict__ wsb, float* __restrict__ out)
{
    __shared__ SMem sm;
    __shared__ int is_last;
    const int bx = blockIdx.x, t = threadIdx.x;
    cg::grid_group grid = cg::this_grid();

    // ================= phase 0: prep ======================================
    if (bx < 64) {
        // convert H/P -> bf16 hi/lo
        const float* src = (bx < 32) ? H : P;
        unsigned short* dh = (unsigned short*)(wsb + ((bx < 32) ? B_HBH : B_PBH));
        unsigned short* dl = (unsigned short*)(wsb + ((bx < 32) ? B_HBL : B_PBL));
        const int base = (bx & 31) * 8192;
        #pragma unroll
        for (int k = 0; k < 8; ++k) {
            const int i = base + k * 1024 + t * 4;
            const float4 v = *(const float4*)(src + i);
            const unsigned short h0 = bf16rne(v.x), h1 = bf16rne(v.y),
                                 h2 = bf16rne(v.z), h3 = bf16rne(v.w);
            *(ushort4*)(dh + i) = make_ushort4(h0, h1, h2, h3);
            *(ushort4*)(dl + i) = make_ushort4(bf16rne(v.x - bf16f(h0)),
                                               bf16rne(v.y - bf16f(h1)),
                                               bf16rne(v.z - bf16f(h2)),
                                               bf16rne(v.w - bf16f(h3)));
        }
        if (bx == 0 && t == 0) *(unsigned*)(wsb + B_CTR) = 0u;  // reset last-block ctr
    } else if (bx < 224) {
        // transpose + convert weights to [n][k] bf16
        const int bt = bx - 64;
        const float* src; unsigned short* dst; int ldn, ldk, k0, n0;
        if (bt < 32)       { src = W1;  dst = (unsigned short*)(wsb + B_WT1);
                             ldn = 512; ldk = 256; k0 = (bt >> 3) * 64;       n0 = (bt & 7) * 64; }
        else if (bt < 96)  { const int i = bt - 32;  src = W1g; dst = (unsigned short*)(wsb + B_WT1G);
                             ldn = 512; ldk = 512; k0 = (i >> 3) * 64;        n0 = (i & 7) * 64; }
        else if (bt < 128) { const int i = bt - 96;  src = W2;  dst = (unsigned short*)(wsb + B_WT2);
                             ldn = 256; ldk = 512; k0 = (i >> 2) * 64;        n0 = (i & 3) * 64; }
        else               { const int i = bt - 128; src = W2g; dst = (unsigned short*)(wsb + B_WT2G);
                             ldn = 256; ldk = 512; k0 = (i >> 2) * 64;        n0 = (i & 3) * 64; }
        const int cg2 = t & 15, rr = t >> 4;
        #pragma unroll
        for (int i = 0; i < 4; ++i) {
            const int r = i * 16 + rr;
            const float4 v = *(const float4*)(src + (size_t)(k0 + r) * ldn + n0 + cg2 * 4);
            sm.T[cg2 * 4 + 0][r] = bf16rne(v.x); sm.T[cg2 * 4 + 1][r] = bf16rne(v.y);
            sm.T[cg2 * 4 + 2][r] = bf16rne(v.z); sm.T[cg2 * 4 + 3][r] = bf16rne(v.w);
        }
        __syncthreads();
        #pragma unroll
        for (int i = 0; i < 4; ++i) {
            const int nr = i * 16 + rr;
            *(ushort4*)(dst + (size_t)(n0 + nr) * ldk + k0 + cg2 * 4) =
                *(const ushort4*)&sm.T[nr][cg2 * 4];
        }
    } else {
        // colmean raw partials: 64 rows of P (cb<16) or G, column t
        const int cb = bx - 224;
        const float* M = (cb & 16) ? G : P;
        const float* p = M + (size_t)(cb & 15) * 64 * DX + t;
        float s0 = 0.f, s1 = 0.f, s2 = 0.f, s3 = 0.f;
        #pragma unroll 4
        for (int r = 0; r < 64; r += 4) {
            s0 += p[(r + 0) * DX]; s1 += p[(r + 1) * DX];
            s2 += p[(r + 2) * DX]; s3 += p[(r + 3) * DX];
        }
        ((float*)(wsb + B_CM))[((cb >> 4) * 16 + (cb & 15)) * 256 + t] = (s0 + s1) + (s2 + s3);
    }

    grid.sync();

    // ================= phase 1: hidden GEMM ===============================
    {
        const int mlp = bx >> 7, bi = bx & 127;
        const int m0 = (bi >> 3) * 64, n0 = (bi & 7) * 64;
        const int wv = t >> 6, ln = t & 63;
        const int wr = wv >> 1, wc = wv & 1;

        const unsigned short* hb_h = (const unsigned short*)(wsb + B_HBH);
        const unsigned short* hb_l = (const unsigned short*)(wsb + B_HBL);
        const unsigned short* pb_h = (const unsigned short*)(wsb + B_PBH);
        const unsigned short* pb_l = (const unsigned short*)(wsb + B_PBL);
        const unsigned short* wt   = (const unsigned short*)(wsb + (mlp ? B_WT1G : B_WT1));
        const int ldk = mlp ? 512 : 256;
        const int nc  = mlp ? 8 : 4;

        stage_bf16(hb_h, m0, 0, 256, sm.g.Ah[0], wv, ln);
        stage_bf16(hb_l, m0, 0, 256, sm.g.Al[0], wv, ln);
        stage_bf16(wt,   n0, 0, ldk, sm.g.W[0],  wv, ln);
        asm volatile("s_waitcnt vmcnt(0)" ::: "memory");
        __syncthreads();

        f32x4 zero = {0.f, 0.f, 0.f, 0.f};
        f32x4 acc[2][2] = {{zero, zero}, {zero, zero}};

        int buf = 0;
        for (int c = 0; c < nc; ++c) {
            if (c + 1 < nc) {
                const int cn = c + 1;
                const unsigned short* ah = (mlp && cn >= 4) ? pb_h : hb_h;
                const unsigned short* al = (mlp && cn >= 4) ? pb_l : hb_l;
                stage_bf16(ah, m0, (cn & 3) * 64, 256, sm.g.Ah[buf ^ 1], wv, ln);
                stage_bf16(al, m0, (cn & 3) * 64, 256, sm.g.Al[buf ^ 1], wv, ln);
                stage_bf16(wt, n0, cn * 64,       ldk, sm.g.W[buf ^ 1],  wv, ln);
            }
            #pragma unroll
            for (int kc = 0; kc < 64; kc += 32) {
                uint4 fh[2], fl[2], fw[2];
                #pragma unroll
                for (int s = 0; s < 2; ++s) {
                    const int ra = 32 * wr + 16 * s + (ln & 15);
                    fh[s] = ldsfrag(sm.g.Ah[buf], ra, kc, ln);
                    fl[s] = ldsfrag(sm.g.Al[buf], ra, kc, ln);
                    fw[s] = ldsfrag(sm.g.W[buf], 32 * wc + 16 * s + (ln & 15), kc, ln);
                }
                #pragma unroll
                for (int sr = 0; sr < 2; ++sr)
                    #pragma unroll
                    for (int sc = 0; sc < 2; ++sc) {
                        acc[sr][sc] = MFMA(fh[sr], fw[sc], acc[sr][sc]);
                        acc[sr][sc] = MFMA(fl[sr], fw[sc], acc[sr][sc]);
                    }
            }
            asm volatile("s_waitcnt vmcnt(0)" ::: "memory");
            __syncthreads();
            buf ^= 1;
        }

        const float* bb = mlp ? b1g : b1;
        unsigned short* oh = (unsigned short*)(wsb + (mlp ? B_HGH : B_H1H));
        unsigned short* ol = (unsigned short*)(wsb + (mlp ? B_HGL : B_H1L));
        #pragma unroll
        for (int sc = 0; sc < 2; ++sc) {
            const int C = n0 + 32 * wc + 16 * sc + (ln & 15);
            const float bv = bb[C];
            #pragma unroll
            for (int sr = 0; sr < 2; ++sr)
                #pragma unroll
                for (int r = 0; r < 4; ++r) {
                    const int R = m0 + 32 * wr + 16 * sr + 4 * (ln >> 4) + r;
                    float v = fmaxf(acc[sr][sc][r] + bv, 0.f);
                    const unsigned short h = bf16rne(v);
                    oh[(size_t)R * 512 + C] = h;
                    ol[(size_t)R * 512 + C] = bf16rne(v - bf16f(h));
                }
        }
    }

    grid.sync();

    // ================= phase 2: out GEMM + on-the-fly dot =================
    {
        const int mlp = bx >> 7;
        const int ks  = (bx >> 6) & 1;
        const int m0  = ((bx >> 2) & 15) * 64;
        const int n0  = (bx & 3) * 64;
        const int wv = t >> 6, ln = t & 63;
        const int wr = wv >> 1, wc = wv & 1;

        const unsigned short* ha = (const unsigned short*)(wsb + (mlp ? B_HGH : B_H1H));
        const unsigned short* la = (const unsigned short*)(wsb + (mlp ? B_HGL : B_H1L));
        const unsigned short* wt = (const unsigned short*)(wsb + (mlp ? B_WT2G : B_WT2));
        const float* Y  = mlp ? G : P;
        const float* cm = (const float*)(wsb + B_CM) + mlp * 4096;
        const int kb = ks * 256;

        stage_bf16(ha, m0, kb, 512, sm.g.Ah[0], wv, ln);
        stage_bf16(la, m0, kb, 512, sm.g.Al[0], wv, ln);
        stage_bf16(wt, n0, kb, 512, sm.g.W[0],  wv, ln);
        asm volatile("s_waitcnt vmcnt(0)" ::: "memory");
        __syncthreads();

        f32x4 zero = {0.f, 0.f, 0.f, 0.f};
        f32x4 acc[2][2] = {{zero, zero}, {zero, zero}};

        int buf = 0;
        for (int c = 0; c < 4; ++c) {
            if (c + 1 < 4) {
                const int colk = kb + (c + 1) * 64;
                stage_bf16(ha, m0, colk, 512, sm.g.Ah[buf ^ 1], wv, ln);
                stage_bf16(la, m0, colk, 512, sm.g.Al[buf ^ 1], wv, ln);
                stage_bf16(wt, n0, colk, 512, sm.g.W[buf ^ 1],  wv, ln);
            }
            #pragma unroll
            for (int kc = 0; kc < 64; kc += 32) {
                uint4 fh[2], fl[2], fw[2];
                #pragma unroll
                for (int s = 0; s < 2; ++s) {
                    const int ra = 32 * wr + 16 * s + (ln & 15);
                    fh[s] = ldsfrag(sm.g.Ah[buf], ra, kc, ln);
                    fl[s] = ldsfrag(sm.g.Al[buf], ra, kc, ln);
                    fw[s] = ldsfrag(sm.g.W[buf], 32 * wc + 16 * s + (ln & 15), kc, ln);
                }
                #pragma unroll
                for (int sr = 0; sr < 2; ++sr)
                    #pragma unroll
                    for (int sc = 0; sc < 2; ++sc) {
                        acc[sr][sc] = MFMA(fh[sr], fw[sc], acc[sr][sc]);
                        acc[sr][sc] = MFMA(fl[sr], fw[sc], acc[sr][sc]);
                    }
            }
            asm volatile("s_waitcnt vmcnt(0)" ::: "memory");
            __syncthreads();
            buf ^= 1;
        }

        float part = 0.f;
        #pragma unroll
        for (int sc = 0; sc < 2; ++sc) {
            const int C = n0 + 32 * wc + 16 * sc + (ln & 15);
            float s = 0.f;
            #pragma unroll
            for (int st = 0; st < 16; ++st) s += cm[st * 256 + C];
            const float e = s * (1.0f / NR);
            #pragma unroll
            for (int sr = 0; sr < 2; ++sr)
                #pragma unroll
                for (int r = 0; r < 4; ++r) {
                    const int R = m0 + 32 * wr + 16 * sr + 4 * (ln >> 4) + r;
                    part += acc[sr][sc][r] * (Y[(size_t)R * DX + C] - e);
                }
        }
        sm.g.red[t] = part;
        __syncthreads();
        #pragma unroll
        for (int sft = 128; sft > 0; sft >>= 1) {
            if (t < sft) sm.g.red[t] += sm.g.red[t + sft];
            __syncthreads();
        }
        if (t == 0) ((float*)(wsb + B_PART))[bx] = sm.g.red[0];
    }

    // ================= last-block final reduce ============================
    __threadfence();   // release this block's partial (device scope)
    if (t == 0) {
        unsigned prev = atomicAdd((unsigned*)(wsb + B_CTR), 1u);
        is_last = (prev == 255u) ? 1 : 0;
    }
    __syncthreads();
    if (is_last) {
        __threadfence();   // acquire: all partials now visible
        sm.dred[t] = (double)((const float*)(wsb + B_PART))[t];
        __syncthreads();
        #pragma unroll
        for (int s = 128; s > 0; s >>= 1) {
            if (t < s) sm.dred[t] += sm.dred[t + s];
            __syncthreads();
        }
        if (t == 0) out[0] = (float)(sm.dred[0] * (1.0 / NR));
    }
}

// ---------------------------------------------------------------------------
extern "C" void kernel_launch(void* const* d_in, const int* in_sizes, int n_in,
                              void* d_out, int out_size, void* d_ws, size_t ws_size,
                              hipStream_t stream)
{
    const float* H   = (const float*)d_in[0];
    const float* P   = (const float*)d_in[1];
    const float* G   = (const float*)d_in[2];
    const float* W1  = (const float*)d_in[3];
    const float* b1  = (const float*)d_in[4];
    const float* W2  = (const float*)d_in[5];
    // d_in[6] = b2: provably zero contribution
    const float* W1g = (const float*)d_in[7];
    const float* b1g = (const float*)d_in[8];
    const float* W2g = (const float*)d_in[9];
    // d_in[10] = b2g: unused
    char* wsb = (char*)d_ws;
    float* out = (float*)d_out;

    void* args[] = { (void*)&H, (void*)&P, (void*)&G, (void*)&W1, (void*)&b1,
                     (void*)&W1g, (void*)&b1g, (void*)&W2, (void*)&W2g,
                     (void*)&wsb, (void*)&out };
    hipLaunchCooperativeKernel((const void*)fused_kernel, dim3(256), dim3(256),
                               args, 0, stream);
}

// Round 7
// 48.449 us; speedup vs baseline: 2.5410x; 2.5410x over previous
//
#include <hip/hip_runtime.h>

#define NR 1024
#define DX 256
#define HX 512

typedef __bf16 bf16x8 __attribute__((ext_vector_type(8)));
typedef float  f32x4  __attribute__((ext_vector_type(4)));

// ---- ws byte offsets (~4.2 MB used)
#define B_CM    0u         // f32 [2][16][256] raw column sums per 64-row stripe
#define B_PART  32768u     // f32 [256] K2 block partials
#define B_CTR   36864u     // u32 last-block counter (reset by K1 each call)
#define B_H1H   65536u     // ushort [1024][512] Hid1 hi (1 MB)
#define B_H1L   1114112u   // Hid1 lo
#define B_HGH   2162688u   // Hidg hi
#define B_HGL   3211264u   // Hidg lo

__device__ __forceinline__ unsigned short bf16rne(float x) {
    unsigned int u = __float_as_uint(x);
    u = u + 0x7FFFu + ((u >> 16) & 1u);
    return (unsigned short)(u >> 16);
}
__device__ __forceinline__ float bf16f(unsigned short h) {
    return __uint_as_float(((unsigned int)h) << 16);
}

// bf16 LDS tile layout [64 rows][64 k], 128 B/row, 16B-slot swizzle:
// elem (r,k) at byte r*128 + (((k>>3)^(r&7))<<4) + ((k&7)<<1).
// Fragment read (row, k = kc+8*(ln>>4)+0..7):
__device__ __forceinline__ uint4 ldsfrag(const unsigned short* lds, int row, int kc, int ln)
{
    const int slot = ((kc >> 3) + (ln >> 4)) ^ (row & 7);
    return *(const uint4*)((const char*)lds + row * 128 + slot * 16);
}

#define MFMA(a, b, c) __builtin_amdgcn_mfma_f32_16x16x32_bf16(                \
    __builtin_bit_cast(bf16x8, a), __builtin_bit_cast(bf16x8, b), c, 0, 0, 0)

// ---------------------------------------------------------------------------
// K1: hidden GEMM with fused fp32->bf16 conversion. 288 blocks:
//  [0,128)   MLP1 tile 64x64 of relu(H@W1+b1),        K=256
//  [128,256) MLPg tile 64x64 of relu([H|P]@W1g+b1g),  K=512
//  [256,288) colmean raw partials of P,G (+ counter reset)
__global__ __launch_bounds__(256) void k1_hidden(
    const float* __restrict__ H, const float* __restrict__ P, const float* __restrict__ G,
    const float* __restrict__ W1, const float* __restrict__ b1,
    const float* __restrict__ W1g, const float* __restrict__ b1g,
    char* __restrict__ wsb)
{
    __shared__ unsigned short sAh[4096], sAl[4096], sW[4096];
    const int bx = blockIdx.x, t = threadIdx.x;

    if (bx >= 256) {  // colmean: 64 rows of P (cb<16) or G, column t
        const int cb = bx - 256;
        if (cb == 0 && t == 0) *(unsigned*)(wsb + B_CTR) = 0u;
        const float* M = (cb & 16) ? G : P;
        const float* p = M + (size_t)(cb & 15) * 64 * DX + t;
        float s0 = 0.f, s1 = 0.f, s2 = 0.f, s3 = 0.f;
        #pragma unroll 4
        for (int r = 0; r < 64; r += 4) {
            s0 += p[(r + 0) * DX]; s1 += p[(r + 1) * DX];
            s2 += p[(r + 2) * DX]; s3 += p[(r + 3) * DX];
        }
        ((float*)(wsb + B_CM))[((cb >> 4) * 16 + (cb & 15)) * 256 + t] = (s0 + s1) + (s2 + s3);
        return;
    }

    const int mlp = bx >> 7, bi = bx & 127;
    const int m0 = (bi >> 3) * 64, n0 = (bi & 7) * 64;
    const int wv = t >> 6, ln = t & 63;
    const int wr = wv >> 1, wc = wv & 1;

    const float* wt = mlp ? W1g : W1;        // [K][512] row-major
    const int nc = mlp ? 8 : 4;              // 64-k steps

    float4 aR[4];   // A fp32: rows wv*16+i*4+(ln>>4), cols (ln&15)*4..+3
    float  wR[16];  // W fp32: n = n0+ln, k = kb+wv*16 .. +15

    auto loadA = [&](const float* src, int ac) {
        #pragma unroll
        for (int i = 0; i < 4; ++i)
            aR[i] = *(const float4*)(src + (size_t)(m0 + wv * 16 + i * 4 + (ln >> 4)) * DX
                                         + ac + (ln & 15) * 4);
    };
    auto loadW = [&](int kb) {
        #pragma unroll
        for (int j = 0; j < 16; ++j)
            wR[j] = wt[(size_t)(kb + wv * 16 + j) * HX + n0 + ln];
    };
    auto writeTiles = [&]() {
        #pragma unroll
        for (int i = 0; i < 4; ++i) {
            const int r = wv * 16 + i * 4 + (ln >> 4);
            const int kl = 4 * (ln & 15);
            const unsigned short h0 = bf16rne(aR[i].x), h1 = bf16rne(aR[i].y),
                                 h2 = bf16rne(aR[i].z), h3 = bf16rne(aR[i].w);
            const int byo = r * 128 + ((((kl >> 3) ^ (r & 7))) << 4) + ((kl & 7) << 1);
            *(ushort4*)((char*)sAh + byo) = make_ushort4(h0, h1, h2, h3);
            *(ushort4*)((char*)sAl + byo) = make_ushort4(bf16rne(aR[i].x - bf16f(h0)),
                                                         bf16rne(aR[i].y - bf16f(h1)),
                                                         bf16rne(aR[i].z - bf16f(h2)),
                                                         bf16rne(aR[i].w - bf16f(h3)));
        }
        #pragma unroll
        for (int s = 0; s < 2; ++s) {
            const int kl = wv * 16 + s * 8;
            const int byo = ln * 128 + (((kl >> 3) ^ (ln & 7)) << 4);
            *(ushort4*)((char*)sW + byo) =
                make_ushort4(bf16rne(wR[s*8+0]), bf16rne(wR[s*8+1]),
                             bf16rne(wR[s*8+2]), bf16rne(wR[s*8+3]));
            *(ushort4*)((char*)sW + byo + 8) =
                make_ushort4(bf16rne(wR[s*8+4]), bf16rne(wR[s*8+5]),
                             bf16rne(wR[s*8+6]), bf16rne(wR[s*8+7]));
        }
    };

    f32x4 zero = {0.f, 0.f, 0.f, 0.f};
    f32x4 acc[2][2] = {{zero, zero}, {zero, zero}};

    loadA(H, 0);
    loadW(0);
    for (int c = 0; c < nc; ++c) {
        __syncthreads();      // previous step's readers done
        writeTiles();
        if (c + 1 < nc) {     // issue next tile's global loads under the MFMAs
            const int cn = c + 1;
            loadA((mlp && cn >= 4) ? P : H, (cn & 3) * 64);
            loadW(cn * 64);
        }
        __syncthreads();      // LDS ready
        #pragma unroll
        for (int kc = 0; kc < 64; kc += 32) {
            uint4 fh[2], fl[2], fw[2];
            #pragma unroll
            for (int s = 0; s < 2; ++s) {
                const int ra = 32 * wr + 16 * s + (ln & 15);
                fh[s] = ldsfrag(sAh, ra, kc, ln);
                fl[s] = ldsfrag(sAl, ra, kc, ln);
                fw[s] = ldsfrag(sW, 32 * wc + 16 * s + (ln & 15), kc, ln);
            }
            #pragma unroll
            for (int sr = 0; sr < 2; ++sr)
                #pragma unroll
                for (int sc = 0; sc < 2; ++sc) {
                    acc[sr][sc] = MFMA(fh[sr], fw[sc], acc[sr][sc]);
                    acc[sr][sc] = MFMA(fl[sr], fw[sc], acc[sr][sc]);
                }
        }
    }

    const float* bb = mlp ? b1g : b1;
    unsigned short* oh = (unsigned short*)(wsb + (mlp ? B_HGH : B_H1H));
    unsigned short* ol = (unsigned short*)(wsb + (mlp ? B_HGL : B_H1L));
    #pragma unroll
    for (int sc = 0; sc < 2; ++sc) {
        const int C = n0 + 32 * wc + 16 * sc + (ln & 15);
        const float bv = bb[C];
        #pragma unroll
        for (int sr = 0; sr < 2; ++sr)
            #pragma unroll
            for (int r = 0; r < 4; ++r) {
                const int R = m0 + 32 * wr + 16 * sr + 4 * (ln >> 4) + r;
                float v = fmaxf(acc[sr][sc][r] + bv, 0.f);
                const unsigned short h = bf16rne(v);
                oh[(size_t)R * 512 + C] = h;
                ol[(size_t)R * 512 + C] = bf16rne(v - bf16f(h));
            }
    }
}

// ---------------------------------------------------------------------------
// K2: mu = Hid @ W2 (b2 contributes exactly 0 against centered Y) dotted with
// (Y - colmean(Y)) on the fly; last block does the final double reduce.
// 256 blocks: bx = [mlp:1][ksplit:1][rowtile:4][coltile:2]; tile 64x64.
__global__ __launch_bounds__(256) void k2_out(
    const float* __restrict__ P, const float* __restrict__ G,
    const float* __restrict__ W2, const float* __restrict__ W2g,
    char* __restrict__ wsb, float* __restrict__ out)
{
    __shared__ unsigned short sAh[4096], sAl[4096], sW[4096];
    __shared__ float red[256];
    __shared__ double dred[256];
    __shared__ int is_last;

    const int bx = blockIdx.x, t = threadIdx.x;
    const int mlp = bx >> 7;
    const int ks  = (bx >> 6) & 1;
    const int m0  = ((bx >> 2) & 15) * 64;
    const int n0  = (bx & 3) * 64;
    const int wv = t >> 6, ln = t & 63;
    const int wr = wv >> 1, wc = wv & 1;

    const unsigned short* ha = (const unsigned short*)(wsb + (mlp ? B_HGH : B_H1H));
    const unsigned short* la = (const unsigned short*)(wsb + (mlp ? B_HGL : B_H1L));
    const float* wt = mlp ? W2g : W2;        // [512][256] row-major
    const float* Y  = mlp ? G : P;
    const float* cm = (const float*)(wsb + B_CM) + mlp * 4096;
    const int kb = ks * 256;

    uint4 hR[2], lR[2];   // Hid bf16: rows i*32+wv*8+(ln>>3), k = 8*(ln&7)..+7
    float wR[16];

    auto loadA = [&](int kt) {
        #pragma unroll
        for (int i = 0; i < 2; ++i) {
            const size_t off = (size_t)(m0 + i * 32 + wv * 8 + (ln >> 3)) * 512 + kt + 8 * (ln & 7);
            hR[i] = *(const uint4*)(ha + off);
            lR[i] = *(const uint4*)(la + off);
        }
    };
    auto loadW = [&](int kt) {
        #pragma unroll
        for (int j = 0; j < 16; ++j)
            wR[j] = wt[(size_t)(kt + wv * 16 + j) * DX + n0 + ln];
    };
    auto writeTiles = [&]() {
        #pragma unroll
        for (int i = 0; i < 2; ++i) {
            const int r = i * 32 + wv * 8 + (ln >> 3);
            const int byo = r * 128 + (((ln & 7) ^ (r & 7)) << 4);
            *(uint4*)((char*)sAh + byo) = hR[i];
            *(uint4*)((char*)sAl + byo) = lR[i];
        }
        #pragma unroll
        for (int s = 0; s < 2; ++s) {
            const int kl = wv * 16 + s * 8;
            const int byo = ln * 128 + (((kl >> 3) ^ (ln & 7)) << 4);
            *(ushort4*)((char*)sW + byo) =
                make_ushort4(bf16rne(wR[s*8+0]), bf16rne(wR[s*8+1]),
                             bf16rne(wR[s*8+2]), bf16rne(wR[s*8+3]));
            *(ushort4*)((char*)sW + byo + 8) =
                make_ushort4(bf16rne(wR[s*8+4]), bf16rne(wR[s*8+5]),
                             bf16rne(wR[s*8+6]), bf16rne(wR[s*8+7]));
        }
    };

    f32x4 zero = {0.f, 0.f, 0.f, 0.f};
    f32x4 acc[2][2] = {{zero, zero}, {zero, zero}};

    loadA(kb);
    loadW(kb);
    for (int c = 0; c < 4; ++c) {
        __syncthreads();
        writeTiles();
        if (c + 1 < 4) {
            loadA(kb + (c + 1) * 64);
            loadW(kb + (c + 1) * 64);
        }
        __syncthreads();
        #pragma unroll
        for (int kc = 0; kc < 64; kc += 32) {
            uint4 fh[2], fl[2], fw[2];
            #pragma unroll
            for (int s = 0; s < 2; ++s) {
                const int ra = 32 * wr + 16 * s + (ln & 15);
                fh[s] = ldsfrag(sAh, ra, kc, ln);
                fl[s] = ldsfrag(sAl, ra, kc, ln);
                fw[s] = ldsfrag(sW, 32 * wc + 16 * s + (ln & 15), kc, ln);
            }
            #pragma unroll
            for (int sr = 0; sr < 2; ++sr)
                #pragma unroll
                for (int sc = 0; sc < 2; ++sc) {
                    acc[sr][sc] = MFMA(fh[sr], fw[sc], acc[sr][sc]);
                    acc[sr][sc] = MFMA(fl[sr], fw[sc], acc[sr][sc]);
                }
        }
    }

    float part = 0.f;
    #pragma unroll
    for (int sc = 0; sc < 2; ++sc) {
        const int C = n0 + 32 * wc + 16 * sc + (ln & 15);
        float s = 0.f;
        #pragma unroll
        for (int st = 0; st < 16; ++st) s += cm[st * 256 + C];
        const float e = s * (1.0f / NR);
        #pragma unroll
        for (int sr = 0; sr < 2; ++sr)
            #pragma unroll
            for (int r = 0; r < 4; ++r) {
                const int R = m0 + 32 * wr + 16 * sr + 4 * (ln >> 4) + r;
                part += acc[sr][sc][r] * (Y[(size_t)R * DX + C] - e);
            }
    }
    red[t] = part;
    __syncthreads();
    #pragma unroll
    for (int sft = 128; sft > 0; sft >>= 1) {
        if (t < sft) red[t] += red[t + sft];
        __syncthreads();
    }
    if (t == 0) ((float*)(wsb + B_PART))[bx] = red[0];

    // last-block final reduce (deterministic fixed-order tree)
    __threadfence();
    if (t == 0) {
        unsigned prev = atomicAdd((unsigned*)(wsb + B_CTR), 1u);
        is_last = (prev == 255u) ? 1 : 0;
    }
    __syncthreads();
    if (is_last) {
        __threadfence();
        dred[t] = (double)((const float*)(wsb + B_PART))[t];
        __syncthreads();
        #pragma unroll
        for (int s = 128; s > 0; s >>= 1) {
            if (t < s) dred[t] += dred[t + s];
            __syncthreads();
        }
        if (t == 0) out[0] = (float)(dred[0] * (1.0 / NR));
    }
}

// ---------------------------------------------------------------------------
extern "C" void kernel_launch(void* const* d_in, const int* in_sizes, int n_in,
                              void* d_out, int out_size, void* d_ws, size_t ws_size,
                              hipStream_t stream)
{
    const float* H   = (const float*)d_in[0];
    const float* P   = (const float*)d_in[1];
    const float* G   = (const float*)d_in[2];
    const float* W1  = (const float*)d_in[3];
    const float* b1  = (const float*)d_in[4];
    const float* W2  = (const float*)d_in[5];
    // d_in[6] = b2: provably zero contribution
    const float* W1g = (const float*)d_in[7];
    const float* b1g = (const float*)d_in[8];
    const float* W2g = (const float*)d_in[9];
    // d_in[10] = b2g: unused
    char* wsb = (char*)d_ws;
    float* out = (float*)d_out;

    hipLaunchKernelGGL(k1_hidden, dim3(288), dim3(256), 0, stream,
                       H, P, G, W1, b1, W1g, b1g, wsb);
    hipLaunchKernelGGL(k2_out,    dim3(256), dim3(256), 0, stream,
                       P, G, W2, W2g, wsb, out);
}

// Round 8
// 47.209 us; speedup vs baseline: 2.6077x; 1.0263x over previous
//
#include <hip/hip_runtime.h>

#define NR 1024
#define DX 256
#define HX 512

typedef __bf16 bf16x8 __attribute__((ext_vector_type(8)));
typedef float  f32x4  __attribute__((ext_vector_type(4)));

// ---- ws byte offsets (~7.3 MB used)
#define B_CM    0u         // f32 [2][16][256] raw column sums per 64-row stripe
#define B_PART  32768u     // f32 [256] gemm_out block partials
#define B_CTR   36864u     // u32 last-block counter (reset by prep each call)
#define B_HBH   65536u     // ushort [1024][256]  H hi
#define B_HBL   589824u    // H lo
#define B_PBH   1114112u   // P hi
#define B_PBL   1638400u   // P lo
#define B_WT1   2162688u   // ushort [512][256]  W1^T bf16
#define B_WT1G  2424832u   // ushort [512][512]  W1g^T
#define B_WT2   2949120u   // ushort [256][512]  W2^T
#define B_WT2G  3211264u   // ushort [256][512]  W2g^T
#define B_H1H   3473408u   // ushort [1024][512] Hid1 hi
#define B_H1L   4521984u   // Hid1 lo
#define B_HGH   5570560u   // Hidg hi
#define B_HGL   6619136u   // Hidg lo

#define GLDS16(gp, lp) __builtin_amdgcn_global_load_lds(                     \
    (const __attribute__((address_space(1))) void*)(gp),                     \
    (__attribute__((address_space(3))) void*)(lp), 16, 0, 0)

__device__ __forceinline__ unsigned short bf16rne(float x) {
    unsigned int u = __float_as_uint(x);
    u = u + 0x7FFFu + ((u >> 16) & 1u);
    return (unsigned short)(u >> 16);
}
__device__ __forceinline__ float bf16f(unsigned short h) {
    return __uint_as_float(((unsigned int)h) << 16);
}

// ---------------------------------------------------------------------------
// Stage a 64x64-bf16 tile (row stride ld elems) into LDS [64][64] with 16B-slot
// swizzle slot' = slot ^ (row&7), applied by permuting the per-lane GLOBAL
// source (global_load_lds writes linearly, rule 21).
__device__ __forceinline__ void stage_bf16(const unsigned short* src, int r0, int c0,
                                           int ld, unsigned short* lds, int wv, int ln)
{
    const int gsl = (ln & 7) ^ ((ln >> 3) & 7);
    #pragma unroll
    for (int i = 0; i < 2; ++i) {
        const int ins = wv * 2 + i;               // 1 KB chunk id 0..7 (8 rows each)
        const unsigned short* gp =
            src + (size_t)(r0 + ins * 8 + (ln >> 3)) * ld + c0 + gsl * 8;
        GLDS16(gp, lds + ins * 512);
    }
}

// Fragment read: 8 consecutive bf16 of (row, k=kc+8*(ln>>4)..+8), swizzled slot.
__device__ __forceinline__ uint4 ldsfrag(const unsigned short* lds, int row, int kc, int ln)
{
    const int slot = ((kc >> 3) + (ln >> 4)) ^ (row & 7);
    return *(const uint4*)((const char*)lds + row * 128 + slot * 16);
}

#define MFMA(a, b, c) __builtin_amdgcn_mfma_f32_16x16x32_bf16(                \
    __builtin_bit_cast(bf16x8, a), __builtin_bit_cast(bf16x8, b), c, 0, 0, 0)

// ---------------------------------------------------------------------------
// K0: prep. blocks [0,64): convert H/P -> bf16 hi/lo. [64,224): transpose+
// convert weights to [n][k] bf16. [224,256): colmean raw partials.
__global__ __launch_bounds__(256) void prep_kernel(
    const float* __restrict__ H, const float* __restrict__ P, const float* __restrict__ G,
    const float* __restrict__ W1, const float* __restrict__ W1g,
    const float* __restrict__ W2, const float* __restrict__ W2g,
    char* __restrict__ wsb)
{
    __shared__ unsigned short T[64][72];
    const int bx = blockIdx.x, t = threadIdx.x;

    if (bx < 64) {
        if (bx == 0 && t == 0) *(unsigned*)(wsb + B_CTR) = 0u;  // reset last-block ctr
        const float* src = (bx < 32) ? H : P;
        unsigned short* dh = (unsigned short*)(wsb + ((bx < 32) ? B_HBH : B_PBH));
        unsigned short* dl = (unsigned short*)(wsb + ((bx < 32) ? B_HBL : B_PBL));
        const int base = (bx & 31) * 8192;
        #pragma unroll
        for (int k = 0; k < 8; ++k) {
            const int i = base + k * 1024 + t * 4;
            const float4 v = *(const float4*)(src + i);
            const unsigned short h0 = bf16rne(v.x), h1 = bf16rne(v.y),
                                 h2 = bf16rne(v.z), h3 = bf16rne(v.w);
            *(ushort4*)(dh + i) = make_ushort4(h0, h1, h2, h3);
            *(ushort4*)(dl + i) = make_ushort4(bf16rne(v.x - bf16f(h0)),
                                               bf16rne(v.y - bf16f(h1)),
                                               bf16rne(v.z - bf16f(h2)),
                                               bf16rne(v.w - bf16f(h3)));
        }
        return;
    }
    if (bx < 224) {
        const int bt = bx - 64;
        const float* src; unsigned short* dst; int ldn, ldk, k0, n0;
        if (bt < 32)       { src = W1;  dst = (unsigned short*)(wsb + B_WT1);
                             ldn = 512; ldk = 256; k0 = (bt >> 3) * 64;       n0 = (bt & 7) * 64; }
        else if (bt < 96)  { const int i = bt - 32;  src = W1g; dst = (unsigned short*)(wsb + B_WT1G);
                             ldn = 512; ldk = 512; k0 = (i >> 3) * 64;        n0 = (i & 7) * 64; }
        else if (bt < 128) { const int i = bt - 96;  src = W2;  dst = (unsigned short*)(wsb + B_WT2);
                             ldn = 256; ldk = 512; k0 = (i >> 2) * 64;        n0 = (i & 3) * 64; }
        else               { const int i = bt - 128; src = W2g; dst = (unsigned short*)(wsb + B_WT2G);
                             ldn = 256; ldk = 512; k0 = (i >> 2) * 64;        n0 = (i & 3) * 64; }
        const int cg = t & 15, rr = t >> 4;
        #pragma unroll
        for (int i = 0; i < 4; ++i) {
            const int r = i * 16 + rr;
            const float4 v = *(const float4*)(src + (size_t)(k0 + r) * ldn + n0 + cg * 4);
            T[cg * 4 + 0][r] = bf16rne(v.x); T[cg * 4 + 1][r] = bf16rne(v.y);
            T[cg * 4 + 2][r] = bf16rne(v.z); T[cg * 4 + 3][r] = bf16rne(v.w);
        }
        __syncthreads();
        #pragma unroll
        for (int i = 0; i < 4; ++i) {
            const int nr = i * 16 + rr;
            *(ushort4*)(dst + (size_t)(n0 + nr) * ldk + k0 + cg * 4) =
                *(const ushort4*)&T[nr][cg * 4];
        }
        return;
    }
    // colmean raw partials: 64 rows of P (cb<16) or G, column t
    const int cb = bx - 224;
    const float* M = (cb & 16) ? G : P;
    const float* p = M + (size_t)(cb & 15) * 64 * DX + t;
    float s0 = 0.f, s1 = 0.f, s2 = 0.f, s3 = 0.f;
    #pragma unroll 4
    for (int r = 0; r < 64; r += 4) {
        s0 += p[(r + 0) * DX]; s1 += p[(r + 1) * DX];
        s2 += p[(r + 2) * DX]; s3 += p[(r + 3) * DX];
    }
    ((float*)(wsb + B_CM))[((cb >> 4) * 16 + (cb & 15)) * 256 + t] = (s0 + s1) + (s2 + s3);
}

// ---------------------------------------------------------------------------
// K1: hidden GEMM, MFMA. 256 blocks: [0,128) MLP1, [128,256) MLPg.
// Block tile 64x64; 4 waves in 2x2; per-wave 32x32 (2x2 subtiles 16x16).
// acc += Ah*W + Al*W over K. Epilogue +b1, relu, store bf16 hi/lo.
__global__ __launch_bounds__(256) void gemm_hidden(
    const float* __restrict__ b1, const float* __restrict__ b1g, char* __restrict__ wsb)
{
    __shared__ unsigned short sAh[2][4096], sAl[2][4096], sW[2][4096];
    const int bx = blockIdx.x, t = threadIdx.x;
    const int mlp = bx >> 7, bi = bx & 127;
    const int m0 = (bi >> 3) * 64, n0 = (bi & 7) * 64;
    const int wv = t >> 6, ln = t & 63;
    const int wr = wv >> 1, wc = wv & 1;

    const unsigned short* hb_h = (const unsigned short*)(wsb + B_HBH);
    const unsigned short* hb_l = (const unsigned short*)(wsb + B_HBL);
    const unsigned short* pb_h = (const unsigned short*)(wsb + B_PBH);
    const unsigned short* pb_l = (const unsigned short*)(wsb + B_PBL);
    const unsigned short* wt   = (const unsigned short*)(wsb + (mlp ? B_WT1G : B_WT1));
    const int ldk = mlp ? 512 : 256;
    const int nc  = mlp ? 8 : 4;

    stage_bf16(hb_h, m0, 0, 256, sAh[0], wv, ln);
    stage_bf16(hb_l, m0, 0, 256, sAl[0], wv, ln);
    stage_bf16(wt,   n0, 0, ldk, sW[0],  wv, ln);
    asm volatile("s_waitcnt vmcnt(0)" ::: "memory");
    __syncthreads();

    f32x4 zero = {0.f, 0.f, 0.f, 0.f};
    f32x4 acc[2][2] = {{zero, zero}, {zero, zero}};

    int buf = 0;
    for (int c = 0; c < nc; ++c) {
        if (c + 1 < nc) {
            const int cn = c + 1;
            const unsigned short* ah = (mlp && cn >= 4) ? pb_h : hb_h;
            const unsigned short* al = (mlp && cn >= 4) ? pb_l : hb_l;
            stage_bf16(ah, m0, (cn & 3) * 64, 256, sAh[buf ^ 1], wv, ln);
            stage_bf16(al, m0, (cn & 3) * 64, 256, sAl[buf ^ 1], wv, ln);
            stage_bf16(wt, n0, cn * 64,       ldk, sW[buf ^ 1],  wv, ln);
        }
        #pragma unroll
        for (int kc = 0; kc < 64; kc += 32) {
            uint4 fh[2], fl[2], fw[2];
            #pragma unroll
            for (int s = 0; s < 2; ++s) {
                const int ra = 32 * wr + 16 * s + (ln & 15);
                fh[s] = ldsfrag(sAh[buf], ra, kc, ln);
                fl[s] = ldsfrag(sAl[buf], ra, kc, ln);
                fw[s] = ldsfrag(sW[buf], 32 * wc + 16 * s + (ln & 15), kc, ln);
            }
            #pragma unroll
            for (int sr = 0; sr < 2; ++sr)
                #pragma unroll
                for (int sc = 0; sc < 2; ++sc) {
                    acc[sr][sc] = MFMA(fh[sr], fw[sc], acc[sr][sc]);
                    acc[sr][sc] = MFMA(fl[sr], fw[sc], acc[sr][sc]);
                }
        }
        asm volatile("s_waitcnt vmcnt(0)" ::: "memory");
        __syncthreads();
        buf ^= 1;
    }

    const float* bb = mlp ? b1g : b1;
    unsigned short* oh = (unsigned short*)(wsb + (mlp ? B_HGH : B_H1H));
    unsigned short* ol = (unsigned short*)(wsb + (mlp ? B_HGL : B_H1L));
    #pragma unroll
    for (int sc = 0; sc < 2; ++sc) {
        const int C = n0 + 32 * wc + 16 * sc + (ln & 15);
        const float bv = bb[C];
        #pragma unroll
        for (int sr = 0; sr < 2; ++sr)
            #pragma unroll
            for (int r = 0; r < 4; ++r) {
                const int R = m0 + 32 * wr + 16 * sr + 4 * (ln >> 4) + r;
                float v = fmaxf(acc[sr][sc][r] + bv, 0.f);
                const unsigned short h = bf16rne(v);
                oh[(size_t)R * 512 + C] = h;
                ol[(size_t)R * 512 + C] = bf16rne(v - bf16f(h));
            }
    }
}

// ---------------------------------------------------------------------------
// K2: mu = Hid @ W2 (b2 contributes exactly 0 against centered Y) dotted with
// (Y - colmean(Y)) on the fly; last block does the final double reduce.
// 256 blocks: bx = [mlp:1][ksplit:1][rowtile:4][coltile:2]; tile 64x64.
__global__ __launch_bounds__(256) void gemm_out(
    const float* __restrict__ P, const float* __restrict__ G, char* __restrict__ wsb,
    float* __restrict__ out)
{
    __shared__ unsigned short sAh[2][4096], sAl[2][4096], sW[2][4096];
    __shared__ float red[256];
    __shared__ double dred[256];
    __shared__ int is_last;
    const int bx = blockIdx.x, t = threadIdx.x;
    const int mlp = bx >> 7;
    const int ks  = (bx >> 6) & 1;
    const int m0  = ((bx >> 2) & 15) * 64;
    const int n0  = (bx & 3) * 64;
    const int wv = t >> 6, ln = t & 63;
    const int wr = wv >> 1, wc = wv & 1;

    const unsigned short* ha = (const unsigned short*)(wsb + (mlp ? B_HGH : B_H1H));
    const unsigned short* la = (const unsigned short*)(wsb + (mlp ? B_HGL : B_H1L));
    const unsigned short* wt = (const unsigned short*)(wsb + (mlp ? B_WT2G : B_WT2));
    const float* Y  = mlp ? G : P;
    const float* cm = (const float*)(wsb + B_CM) + mlp * 4096;
    const int kb = ks * 256;

    stage_bf16(ha, m0, kb, 512, sAh[0], wv, ln);
    stage_bf16(la, m0, kb, 512, sAl[0], wv, ln);
    stage_bf16(wt, n0, kb, 512, sW[0],  wv, ln);
    asm volatile("s_waitcnt vmcnt(0)" ::: "memory");
    __syncthreads();

    f32x4 zero = {0.f, 0.f, 0.f, 0.f};
    f32x4 acc[2][2] = {{zero, zero}, {zero, zero}};

    int buf = 0;
    for (int c = 0; c < 4; ++c) {
        if (c + 1 < 4) {
            const int colk = kb + (c + 1) * 64;
            stage_bf16(ha, m0, colk, 512, sAh[buf ^ 1], wv, ln);
            stage_bf16(la, m0, colk, 512, sAl[buf ^ 1], wv, ln);
            stage_bf16(wt, n0, colk, 512, sW[buf ^ 1],  wv, ln);
        }
        #pragma unroll
        for (int kc = 0; kc < 64; kc += 32) {
            uint4 fh[2], fl[2], fw[2];
            #pragma unroll
            for (int s = 0; s < 2; ++s) {
                const int ra = 32 * wr + 16 * s + (ln & 15);
                fh[s] = ldsfrag(sAh[buf], ra, kc, ln);
                fl[s] = ldsfrag(sAl[buf], ra, kc, ln);
                fw[s] = ldsfrag(sW[buf], 32 * wc + 16 * s + (ln & 15), kc, ln);
            }
            #pragma unroll
            for (int sr = 0; sr < 2; ++sr)
                #pragma unroll
                for (int sc = 0; sc < 2; ++sc) {
                    acc[sr][sc] = MFMA(fh[sr], fw[sc], acc[sr][sc]);
                    acc[sr][sc] = MFMA(fl[sr], fw[sc], acc[sr][sc]);
                }
        }
        asm volatile("s_waitcnt vmcnt(0)" ::: "memory");
        __syncthreads();
        buf ^= 1;
    }

    float part = 0.f;
    #pragma unroll
    for (int sc = 0; sc < 2; ++sc) {
        const int C = n0 + 32 * wc + 16 * sc + (ln & 15);
        float s = 0.f;
        #pragma unroll
        for (int st = 0; st < 16; ++st) s += cm[st * 256 + C];
        const float e = s * (1.0f / NR);
        #pragma unroll
        for (int sr = 0; sr < 2; ++sr)
            #pragma unroll
            for (int r = 0; r < 4; ++r) {
                const int R = m0 + 32 * wr + 16 * sr + 4 * (ln >> 4) + r;
                part += acc[sr][sc][r] * (Y[(size_t)R * DX + C] - e);
            }
    }
    red[t] = part;
    __syncthreads();
    #pragma unroll
    for (int sft = 128; sft > 0; sft >>= 1) {
        if (t < sft) red[t] += red[t + sft];
        __syncthreads();
    }
    if (t == 0) ((float*)(wsb + B_PART))[bx] = red[0];

    // last-block final reduce (deterministic fixed-order tree)
    __threadfence();
    if (t == 0) {
        unsigned prev = atomicAdd((unsigned*)(wsb + B_CTR), 1u);
        is_last = (prev == 255u) ? 1 : 0;
    }
    __syncthreads();
    if (is_last) {
        __threadfence();
        dred[t] = (double)((const float*)(wsb + B_PART))[t];
        __syncthreads();
        #pragma unroll
        for (int s = 128; s > 0; s >>= 1) {
            if (t < s) dred[t] += dred[t + s];
            __syncthreads();
        }
        if (t == 0) out[0] = (float)(dred[0] * (1.0 / NR));
    }
}

// ---------------------------------------------------------------------------
extern "C" void kernel_launch(void* const* d_in, const int* in_sizes, int n_in,
                              void* d_out, int out_size, void* d_ws, size_t ws_size,
                              hipStream_t stream)
{
    const float* H   = (const float*)d_in[0];
    const float* P   = (const float*)d_in[1];
    const float* G   = (const float*)d_in[2];
    const float* W1  = (const float*)d_in[3];
    const float* b1  = (const float*)d_in[4];
    const float* W2  = (const float*)d_in[5];
    // d_in[6] = b2: provably zero contribution
    const float* W1g = (const float*)d_in[7];
    const float* b1g = (const float*)d_in[8];
    const float* W2g = (const float*)d_in[9];
    // d_in[10] = b2g: unused
    char* wsb = (char*)d_ws;
    float* out = (float*)d_out;

    hipLaunchKernelGGL(prep_kernel, dim3(256), dim3(256), 0, stream,
                       H, P, G, W1, W1g, W2, W2g, wsb);
    hipLaunchKernelGGL(gemm_hidden, dim3(256), dim3(256), 0, stream, b1, b1g, wsb);
    hipLaunchKernelGGL(gemm_out,    dim3(256), dim3(256), 0, stream, P, G, wsb, out);
}

// Round 9
// 30.302 us; speedup vs baseline: 4.0626x; 1.5579x over previous
//
#include <hip/hip_runtime.h>

#define NR 1024
#define DX 256
#define HX 512

typedef __bf16 bf16x8 __attribute__((ext_vector_type(8)));
typedef float  f32x4  __attribute__((ext_vector_type(4)));

// ---- ws byte offsets (~7.3 MB used)
#define B_CM    0u         // f32 [2][16][256] raw column sums per 64-row stripe
#define B_CTR   36864u     // u32 completion counter (reset by prep each call)
#define B_TOT   36928u     // u64 fixed-point grand total (reset by prep each call)
#define B_HBH   65536u     // ushort [1024][256]  H hi
#define B_HBL   589824u    // H lo
#define B_PBH   1114112u   // P hi
#define B_PBL   1638400u   // P lo
#define B_WT1   2162688u   // ushort [512][256]  W1^T bf16
#define B_WT1G  2424832u   // ushort [512][512]  W1g^T
#define B_WT2   2949120u   // ushort [256][512]  W2^T
#define B_WT2G  3211264u   // ushort [256][512]  W2g^T
#define B_H1H   3473408u   // ushort [1024][512] Hid1 hi
#define B_H1L   4521984u   // Hid1 lo
#define B_HGH   5570560u   // Hidg hi
#define B_HGL   6619136u   // Hidg lo

#define FIXSCALE 1099511627776.0   // 2^40

#define GLDS16(gp, lp) __builtin_amdgcn_global_load_lds(                     \
    (const __attribute__((address_space(1))) void*)(gp),                     \
    (__attribute__((address_space(3))) void*)(lp), 16, 0, 0)

__device__ __forceinline__ unsigned short bf16rne(float x) {
    unsigned int u = __float_as_uint(x);
    u = u + 0x7FFFu + ((u >> 16) & 1u);
    return (unsigned short)(u >> 16);
}
__device__ __forceinline__ float bf16f(unsigned short h) {
    return __uint_as_float(((unsigned int)h) << 16);
}

// ---------------------------------------------------------------------------
// Stage a 64x64-bf16 tile (row stride ld elems) into LDS [64][64] with 16B-slot
// swizzle slot' = slot ^ (row&7), applied by permuting the per-lane GLOBAL
// source (global_load_lds writes linearly, rule 21).
__device__ __forceinline__ void stage_bf16(const unsigned short* src, int r0, int c0,
                                           int ld, unsigned short* lds, int wv, int ln)
{
    const int gsl = (ln & 7) ^ ((ln >> 3) & 7);
    #pragma unroll
    for (int i = 0; i < 2; ++i) {
        const int ins = wv * 2 + i;               // 1 KB chunk id 0..7 (8 rows each)
        const unsigned short* gp =
            src + (size_t)(r0 + ins * 8 + (ln >> 3)) * ld + c0 + gsl * 8;
        GLDS16(gp, lds + ins * 512);
    }
}

// Fragment read: 8 consecutive bf16 of (row, k=kc+8*(ln>>4)..+8), swizzled slot.
__device__ __forceinline__ uint4 ldsfrag(const unsigned short* lds, int row, int kc, int ln)
{
    const int slot = ((kc >> 3) + (ln >> 4)) ^ (row & 7);
    return *(const uint4*)((const char*)lds + row * 128 + slot * 16);
}

#define MFMA(a, b, c) __builtin_amdgcn_mfma_f32_16x16x32_bf16(                \
    __builtin_bit_cast(bf16x8, a), __builtin_bit_cast(bf16x8, b), c, 0, 0, 0)

// ---------------------------------------------------------------------------
// K0: prep. blocks [0,64): convert H/P -> bf16 hi/lo. [64,224): transpose+
// convert weights to [n][k] bf16. [224,256): colmean raw partials.
__global__ __launch_bounds__(256) void prep_kernel(
    const float* __restrict__ H, const float* __restrict__ P, const float* __restrict__ G,
    const float* __restrict__ W1, const float* __restrict__ W1g,
    const float* __restrict__ W2, const float* __restrict__ W2g,
    char* __restrict__ wsb)
{
    __shared__ unsigned short T[64][72];
    const int bx = blockIdx.x, t = threadIdx.x;

    if (bx < 64) {
        if (bx == 0 && t == 0) {       // reset last-block counter + fixed-point total
            *(unsigned*)(wsb + B_CTR) = 0u;
            *(unsigned long long*)(wsb + B_TOT) = 0ull;
        }
        const float* src = (bx < 32) ? H : P;
        unsigned short* dh = (unsigned short*)(wsb + ((bx < 32) ? B_HBH : B_PBH));
        unsigned short* dl = (unsigned short*)(wsb + ((bx < 32) ? B_HBL : B_PBL));
        const int base = (bx & 31) * 8192;
        #pragma unroll
        for (int k = 0; k < 8; ++k) {
            const int i = base + k * 1024 + t * 4;
            const float4 v = *(const float4*)(src + i);
            const unsigned short h0 = bf16rne(v.x), h1 = bf16rne(v.y),
                                 h2 = bf16rne(v.z), h3 = bf16rne(v.w);
            *(ushort4*)(dh + i) = make_ushort4(h0, h1, h2, h3);
            *(ushort4*)(dl + i) = make_ushort4(bf16rne(v.x - bf16f(h0)),
                                               bf16rne(v.y - bf16f(h1)),
                                               bf16rne(v.z - bf16f(h2)),
                                               bf16rne(v.w - bf16f(h3)));
        }
        return;
    }
    if (bx < 224) {
        const int bt = bx - 64;
        const float* src; unsigned short* dst; int ldn, ldk, k0, n0;
        if (bt < 32)       { src = W1;  dst = (unsigned short*)(wsb + B_WT1);
                             ldn = 512; ldk = 256; k0 = (bt >> 3) * 64;       n0 = (bt & 7) * 64; }
        else if (bt < 96)  { const int i = bt - 32;  src = W1g; dst = (unsigned short*)(wsb + B_WT1G);
                             ldn = 512; ldk = 512; k0 = (i >> 3) * 64;        n0 = (i & 7) * 64; }
        else if (bt < 128) { const int i = bt - 96;  src = W2;  dst = (unsigned short*)(wsb + B_WT2);
                             ldn = 256; ldk = 512; k0 = (i >> 2) * 64;        n0 = (i & 3) * 64; }
        else               { const int i = bt - 128; src = W2g; dst = (unsigned short*)(wsb + B_WT2G);
                             ldn = 256; ldk = 512; k0 = (i >> 2) * 64;        n0 = (i & 3) * 64; }
        const int cg = t & 15, rr = t >> 4;
        #pragma unroll
        for (int i = 0; i < 4; ++i) {
            const int r = i * 16 + rr;
            const float4 v = *(const float4*)(src + (size_t)(k0 + r) * ldn + n0 + cg * 4);
            T[cg * 4 + 0][r] = bf16rne(v.x); T[cg * 4 + 1][r] = bf16rne(v.y);
            T[cg * 4 + 2][r] = bf16rne(v.z); T[cg * 4 + 3][r] = bf16rne(v.w);
        }
        __syncthreads();
        #pragma unroll
        for (int i = 0; i < 4; ++i) {
            const int nr = i * 16 + rr;
            *(ushort4*)(dst + (size_t)(n0 + nr) * ldk + k0 + cg * 4) =
                *(const ushort4*)&T[nr][cg * 4];
        }
        return;
    }
    // colmean raw partials: 64 rows of P (cb<16) or G, column t
    const int cb = bx - 224;
    const float* M = (cb & 16) ? G : P;
    const float* p = M + (size_t)(cb & 15) * 64 * DX + t;
    float s0 = 0.f, s1 = 0.f, s2 = 0.f, s3 = 0.f;
    #pragma unroll 4
    for (int r = 0; r < 64; r += 4) {
        s0 += p[(r + 0) * DX]; s1 += p[(r + 1) * DX];
        s2 += p[(r + 2) * DX]; s3 += p[(r + 3) * DX];
    }
    ((float*)(wsb + B_CM))[((cb >> 4) * 16 + (cb & 15)) * 256 + t] = (s0 + s1) + (s2 + s3);
}

// ---------------------------------------------------------------------------
// K1: hidden GEMM, MFMA. 256 blocks: [0,128) MLP1, [128,256) MLPg.
// Block tile 64x64; 4 waves in 2x2; per-wave 32x32 (2x2 subtiles 16x16).
// acc += Ah*W + Al*W over K. Epilogue +b1, relu, store bf16 hi/lo.
__global__ __launch_bounds__(256) void gemm_hidden(
    const float* __restrict__ b1, const float* __restrict__ b1g, char* __restrict__ wsb)
{
    __shared__ unsigned short sAh[2][4096], sAl[2][4096], sW[2][4096];
    const int bx = blockIdx.x, t = threadIdx.x;
    const int mlp = bx >> 7, bi = bx & 127;
    const int m0 = (bi >> 3) * 64, n0 = (bi & 7) * 64;
    const int wv = t >> 6, ln = t & 63;
    const int wr = wv >> 1, wc = wv & 1;

    const unsigned short* hb_h = (const unsigned short*)(wsb + B_HBH);
    const unsigned short* hb_l = (const unsigned short*)(wsb + B_HBL);
    const unsigned short* pb_h = (const unsigned short*)(wsb + B_PBH);
    const unsigned short* pb_l = (const unsigned short*)(wsb + B_PBL);
    const unsigned short* wt   = (const unsigned short*)(wsb + (mlp ? B_WT1G : B_WT1));
    const int ldk = mlp ? 512 : 256;
    const int nc  = mlp ? 8 : 4;

    stage_bf16(hb_h, m0, 0, 256, sAh[0], wv, ln);
    stage_bf16(hb_l, m0, 0, 256, sAl[0], wv, ln);
    stage_bf16(wt,   n0, 0, ldk, sW[0],  wv, ln);
    asm volatile("s_waitcnt vmcnt(0)" ::: "memory");
    __syncthreads();

    f32x4 zero = {0.f, 0.f, 0.f, 0.f};
    f32x4 acc[2][2] = {{zero, zero}, {zero, zero}};

    int buf = 0;
    for (int c = 0; c < nc; ++c) {
        if (c + 1 < nc) {
            const int cn = c + 1;
            const unsigned short* ah = (mlp && cn >= 4) ? pb_h : hb_h;
            const unsigned short* al = (mlp && cn >= 4) ? pb_l : hb_l;
            stage_bf16(ah, m0, (cn & 3) * 64, 256, sAh[buf ^ 1], wv, ln);
            stage_bf16(al, m0, (cn & 3) * 64, 256, sAl[buf ^ 1], wv, ln);
            stage_bf16(wt, n0, cn * 64,       ldk, sW[buf ^ 1],  wv, ln);
        }
        #pragma unroll
        for (int kc = 0; kc < 64; kc += 32) {
            uint4 fh[2], fl[2], fw[2];
            #pragma unroll
            for (int s = 0; s < 2; ++s) {
                const int ra = 32 * wr + 16 * s + (ln & 15);
                fh[s] = ldsfrag(sAh[buf], ra, kc, ln);
                fl[s] = ldsfrag(sAl[buf], ra, kc, ln);
                fw[s] = ldsfrag(sW[buf], 32 * wc + 16 * s + (ln & 15), kc, ln);
            }
            #pragma unroll
            for (int sr = 0; sr < 2; ++sr)
                #pragma unroll
                for (int sc = 0; sc < 2; ++sc) {
                    acc[sr][sc] = MFMA(fh[sr], fw[sc], acc[sr][sc]);
                    acc[sr][sc] = MFMA(fl[sr], fw[sc], acc[sr][sc]);
                }
        }
        asm volatile("s_waitcnt vmcnt(0)" ::: "memory");
        __syncthreads();
        buf ^= 1;
    }

    const float* bb = mlp ? b1g : b1;
    unsigned short* oh = (unsigned short*)(wsb + (mlp ? B_HGH : B_H1H));
    unsigned short* ol = (unsigned short*)(wsb + (mlp ? B_HGL : B_H1L));
    #pragma unroll
    for (int sc = 0; sc < 2; ++sc) {
        const int C = n0 + 32 * wc + 16 * sc + (ln & 15);
        const float bv = bb[C];
        #pragma unroll
        for (int sr = 0; sr < 2; ++sr)
            #pragma unroll
            for (int r = 0; r < 4; ++r) {
                const int R = m0 + 32 * wr + 16 * sr + 4 * (ln >> 4) + r;
                float v = fmaxf(acc[sr][sc][r] + bv, 0.f);
                const unsigned short h = bf16rne(v);
                oh[(size_t)R * 512 + C] = h;
                ol[(size_t)R * 512 + C] = bf16rne(v - bf16f(h));
            }
    }
}

// ---------------------------------------------------------------------------
// K2: mu = Hid @ W2 (b2 contributes exactly 0 against centered Y) dotted with
// (Y - colmean(Y)) on the fly. Fence-free deterministic finish: per-block
// partial -> fixed-point (2^40) integer atomicAdd into a single total
// (integer adds commute exactly -> bit-deterministic); the 256th arriver
// reads the total with atomicAdd(+0) and writes d_out. No __threadfence.
// 256 blocks: bx = [mlp:1][ksplit:1][rowtile:4][coltile:2]; tile 64x64.
__global__ __launch_bounds__(256) void gemm_out(
    const float* __restrict__ P, const float* __restrict__ G, char* __restrict__ wsb,
    float* __restrict__ out)
{
    __shared__ unsigned short sAh[2][4096], sAl[2][4096], sW[2][4096];
    __shared__ float red[256];
    const int bx = blockIdx.x, t = threadIdx.x;
    const int mlp = bx >> 7;
    const int ks  = (bx >> 6) & 1;
    const int m0  = ((bx >> 2) & 15) * 64;
    const int n0  = (bx & 3) * 64;
    const int wv = t >> 6, ln = t & 63;
    const int wr = wv >> 1, wc = wv & 1;

    const unsigned short* ha = (const unsigned short*)(wsb + (mlp ? B_HGH : B_H1H));
    const unsigned short* la = (const unsigned short*)(wsb + (mlp ? B_HGL : B_H1L));
    const unsigned short* wt = (const unsigned short*)(wsb + (mlp ? B_WT2G : B_WT2));
    const float* Y  = mlp ? G : P;
    const float* cm = (const float*)(wsb + B_CM) + mlp * 4096;
    const int kb = ks * 256;

    stage_bf16(ha, m0, kb, 512, sAh[0], wv, ln);
    stage_bf16(la, m0, kb, 512, sAl[0], wv, ln);
    stage_bf16(wt, n0, kb, 512, sW[0],  wv, ln);
    asm volatile("s_waitcnt vmcnt(0)" ::: "memory");
    __syncthreads();

    f32x4 zero = {0.f, 0.f, 0.f, 0.f};
    f32x4 acc[2][2] = {{zero, zero}, {zero, zero}};

    int buf = 0;
    for (int c = 0; c < 4; ++c) {
        if (c + 1 < 4) {
            const int colk = kb + (c + 1) * 64;
            stage_bf16(ha, m0, colk, 512, sAh[buf ^ 1], wv, ln);
            stage_bf16(la, m0, colk, 512, sAl[buf ^ 1], wv, ln);
            stage_bf16(wt, n0, colk, 512, sW[buf ^ 1],  wv, ln);
        }
        #pragma unroll
        for (int kc = 0; kc < 64; kc += 32) {
            uint4 fh[2], fl[2], fw[2];
            #pragma unroll
            for (int s = 0; s < 2; ++s) {
                const int ra = 32 * wr + 16 * s + (ln & 15);
                fh[s] = ldsfrag(sAh[buf], ra, kc, ln);
                fl[s] = ldsfrag(sAl[buf], ra, kc, ln);
                fw[s] = ldsfrag(sW[buf], 32 * wc + 16 * s + (ln & 15), kc, ln);
            }
            #pragma unroll
            for (int sr = 0; sr < 2; ++sr)
                #pragma unroll
                for (int sc = 0; sc < 2; ++sc) {
                    acc[sr][sc] = MFMA(fh[sr], fw[sc], acc[sr][sc]);
                    acc[sr][sc] = MFMA(fl[sr], fw[sc], acc[sr][sc]);
                }
        }
        asm volatile("s_waitcnt vmcnt(0)" ::: "memory");
        __syncthreads();
        buf ^= 1;
    }

    float part = 0.f;
    #pragma unroll
    for (int sc = 0; sc < 2; ++sc) {
        const int C = n0 + 32 * wc + 16 * sc + (ln & 15);
        float s = 0.f;
        #pragma unroll
        for (int st = 0; st < 16; ++st) s += cm[st * 256 + C];
        const float e = s * (1.0f / NR);
        #pragma unroll
        for (int sr = 0; sr < 2; ++sr)
            #pragma unroll
            for (int r = 0; r < 4; ++r) {
                const int R = m0 + 32 * wr + 16 * sr + 4 * (ln >> 4) + r;
                part += acc[sr][sc][r] * (Y[(size_t)R * DX + C] - e);
            }
    }
    red[t] = part;
    __syncthreads();
    #pragma unroll
    for (int sft = 128; sft > 0; sft >>= 1) {
        if (t < sft) red[t] += red[t + sft];
        __syncthreads();
    }

    if (t == 0) {
        unsigned long long* tot = (unsigned long long*)(wsb + B_TOT);
        unsigned* ctr = (unsigned*)(wsb + B_CTR);
        const long long ll = llrint((double)red[0] * FIXSCALE);
        atomicAdd(tot, (unsigned long long)ll);
        asm volatile("s_waitcnt vmcnt(0)" ::: "memory");  // total-add performed before ctr-add
        const unsigned prev = atomicAdd(ctr, 1u);
        if (prev == 255u) {
            const unsigned long long s = atomicAdd(tot, 0ull);  // coherent read
            out[0] = (float)((double)(long long)s * (1.0 / FIXSCALE) * (1.0 / NR));
        }
    }
}

// ---------------------------------------------------------------------------
extern "C" void kernel_launch(void* const* d_in, const int* in_sizes, int n_in,
                              void* d_out, int out_size, void* d_ws, size_t ws_size,
                              hipStream_t stream)
{
    const float* H   = (const float*)d_in[0];
    const float* P   = (const float*)d_in[1];
    const float* G   = (const float*)d_in[2];
    const float* W1  = (const float*)d_in[3];
    const float* b1  = (const float*)d_in[4];
    const float* W2  = (const float*)d_in[5];
    // d_in[6] = b2: provably zero contribution
    const float* W1g = (const float*)d_in[7];
    const float* b1g = (const float*)d_in[8];
    const float* W2g = (const float*)d_in[9];
    // d_in[10] = b2g: unused
    char* wsb = (char*)d_ws;
    float* out = (float*)d_out;

    hipLaunchKernelGGL(prep_kernel, dim3(256), dim3(256), 0, stream,
                       H, P, G, W1, W1g, W2, W2g, wsb);
    hipLaunchKernelGGL(gemm_hidden, dim3(256), dim3(256), 0, stream, b1, b1g, wsb);
    hipLaunchKernelGGL(gemm_out,    dim3(256), dim3(256), 0, stream, P, G, wsb, out);
}

// Round 10
// 26.941 us; speedup vs baseline: 4.5696x; 1.1248x over previous
//
#include <hip/hip_runtime.h>

#define NR 1024
#define DX 256
#define HX 512

typedef __bf16 bf16x8 __attribute__((ext_vector_type(8)));
typedef float  f32x4  __attribute__((ext_vector_type(4)));

// ---- ws byte offsets (~4.3 MB used)
#define B_CM    0u         // f32 [2][16][256] raw column sums per 64-row stripe
#define B_CTR   36864u     // u32 completion counter (reset by k1 each call)
#define B_TOT   36928u     // u64 fixed-point grand total (reset by k1 each call)
#define B_H1H   65536u     // ushort [1024][512] Hid1 hi (1 MB)
#define B_H1L   1114112u   // Hid1 lo
#define B_HGH   2162688u   // Hidg hi
#define B_HGL   3211264u   // Hidg lo

#define FIXSCALE 1099511627776.0   // 2^40

#define GLDS16(gp, lp) __builtin_amdgcn_global_load_lds(                     \
    (const __attribute__((address_space(1))) void*)(gp),                     \
    (__attribute__((address_space(3))) void*)(lp), 16, 0, 0)

__device__ __forceinline__ unsigned short bf16rne(float x) {
    unsigned int u = __float_as_uint(x);
    u = u + 0x7FFFu + ((u >> 16) & 1u);
    return (unsigned short)(u >> 16);
}
__device__ __forceinline__ float bf16f(unsigned short h) {
    return __uint_as_float(((unsigned int)h) << 16);
}

// bf16 LDS tile [64 rows][64 k], 128 B/row, 16B-slot swizzle:
// elem (r,k) at byte r*128 + (((k>>3)^(r&7))<<4) + ((k&7)<<1).
__device__ __forceinline__ uint4 ldsfrag(const unsigned short* lds, int row, int kc, int ln)
{
    const int slot = ((kc >> 3) + (ln >> 4)) ^ (row & 7);
    return *(const uint4*)((const char*)lds + row * 128 + slot * 16);
}

// Stage a 64x64-bf16 tile (row stride ld) via global_load_lds, swizzle applied
// by permuting the per-lane GLOBAL source (LDS dst stays linear, rule 21).
__device__ __forceinline__ void stage_bf16(const unsigned short* src, int r0, int c0,
                                           int ld, unsigned short* lds, int wv, int ln)
{
    const int gsl = (ln & 7) ^ ((ln >> 3) & 7);
    #pragma unroll
    for (int i = 0; i < 2; ++i) {
        const int ins = wv * 2 + i;
        const unsigned short* gp =
            src + (size_t)(r0 + ins * 8 + (ln >> 3)) * ld + c0 + gsl * 8;
        GLDS16(gp, lds + ins * 512);
    }
}

#define MFMA(a, b, c) __builtin_amdgcn_mfma_f32_16x16x32_bf16(                \
    __builtin_bit_cast(bf16x8, a), __builtin_bit_cast(bf16x8, b), c, 0, 0, 0)

// ---------------------------------------------------------------------------
// Hidden GEMM body with in-pipeline fp32->bf16(hi/lo) conversion.
// Tile 64x64, NC 64-k steps. Double-buffered LDS, one barrier per step:
//   iter c: MFMA(buf b) || convert+ds_write buf 1-b (data c+1, regs loaded
//   at iter c-1) || issue global loads for c+2.
template<int NC>
__device__ __forceinline__ void hidden_body(
    const float* __restrict__ A0, const float* __restrict__ A1,
    const float* __restrict__ Wsrc, const float* __restrict__ bb,
    unsigned short* __restrict__ oh, unsigned short* __restrict__ ol,
    unsigned short (*sAh)[4096], unsigned short (*sAl)[4096],
    unsigned short (*sW)[4096],
    int m0, int n0, int wv, int ln)
{
    const int wr = wv >> 1, wc = wv & 1;

    float4 aR[2][4];   // A fp32: rows wv*16+i*4+(ln>>4), cols (ln&15)*4..+3
    float  wR[2][16];  // W fp32: n = n0+ln, k(tile) = wv*16+j  (coalesced in n)

    auto loadA = [&](int rb, int c) {
        const float* src = (NC == 8 && c >= 4) ? A1 : A0;
        const int ac = (c & 3) * 64;
        #pragma unroll
        for (int i = 0; i < 4; ++i)
            aR[rb][i] = *(const float4*)(src +
                (size_t)(m0 + wv * 16 + i * 4 + (ln >> 4)) * DX + ac + (ln & 15) * 4);
    };
    auto loadW = [&](int rb, int c) {
        #pragma unroll
        for (int j = 0; j < 16; ++j)
            wR[rb][j] = Wsrc[(size_t)(c * 64 + wv * 16 + j) * HX + n0 + ln];
    };
    auto writeT = [&](int rb, int b) {
        #pragma unroll
        for (int i = 0; i < 4; ++i) {
            const int r = wv * 16 + i * 4 + (ln >> 4);
            const int q = ln & 15;    // float4 index in row; k = 4q..4q+3
            const int byo = r * 128 + ((((q >> 1) ^ (r & 7))) << 4) + ((q & 1) << 3);
            const float4 v = aR[rb][i];
            const unsigned short h0 = bf16rne(v.x), h1 = bf16rne(v.y),
                                 h2 = bf16rne(v.z), h3 = bf16rne(v.w);
            *(ushort4*)((char*)sAh[b] + byo) = make_ushort4(h0, h1, h2, h3);
            *(ushort4*)((char*)sAl[b] + byo) =
                make_ushort4(bf16rne(v.x - bf16f(h0)), bf16rne(v.y - bf16f(h1)),
                             bf16rne(v.z - bf16f(h2)), bf16rne(v.w - bf16f(h3)));
        }
        #pragma unroll
        for (int s = 0; s < 2; ++s) {   // row ln, k = wv*16+s*8 .. +7 (transpose)
            const int byo = ln * 128 + ((((2 * wv + s) ^ (ln & 7))) << 4);
            *(ushort4*)((char*)sW[b] + byo) =
                make_ushort4(bf16rne(wR[rb][s*8+0]), bf16rne(wR[rb][s*8+1]),
                             bf16rne(wR[rb][s*8+2]), bf16rne(wR[rb][s*8+3]));
            *(ushort4*)((char*)sW[b] + byo + 8) =
                make_ushort4(bf16rne(wR[rb][s*8+4]), bf16rne(wR[rb][s*8+5]),
                             bf16rne(wR[rb][s*8+6]), bf16rne(wR[rb][s*8+7]));
        }
    };

    f32x4 zero = {0.f, 0.f, 0.f, 0.f};
    f32x4 acc[2][2] = {{zero, zero}, {zero, zero}};

    loadA(0, 0); loadW(0, 0);
    writeT(0, 0);                 // compiler waits the c=0 loads
    loadA(1, 1); loadW(1, 1);     // prefetch c=1 under first MFMA phase
    __syncthreads();

    #pragma unroll
    for (int c = 0; c < NC; ++c) {
        const int b = c & 1;
        #pragma unroll
        for (int kc = 0; kc < 64; kc += 32) {
            uint4 fh[2], fl[2], fw[2];
            #pragma unroll
            for (int s = 0; s < 2; ++s) {
                const int ra = 32 * wr + 16 * s + (ln & 15);
                fh[s] = ldsfrag(sAh[b], ra, kc, ln);
                fl[s] = ldsfrag(sAl[b], ra, kc, ln);
                fw[s] = ldsfrag(sW[b], 32 * wc + 16 * s + (ln & 15), kc, ln);
            }
            #pragma unroll
            for (int sr = 0; sr < 2; ++sr)
                #pragma unroll
                for (int sc = 0; sc < 2; ++sc) {
                    acc[sr][sc] = MFMA(fh[sr], fw[sc], acc[sr][sc]);
                    acc[sr][sc] = MFMA(fl[sr], fw[sc], acc[sr][sc]);
                }
        }
        if (c + 1 < NC) {
            writeT(1 - b, 1 - b);                       // data c+1 -> buf 1-b
            if (c + 2 < NC) { loadA(b, c + 2); loadW(b, c + 2); }
        }
        __syncthreads();
    }

    #pragma unroll
    for (int sc = 0; sc < 2; ++sc) {
        const int C = n0 + 32 * wc + 16 * sc + (ln & 15);
        const float bv = bb[C];
        #pragma unroll
        for (int sr = 0; sr < 2; ++sr)
            #pragma unroll
            for (int r = 0; r < 4; ++r) {
                const int R = m0 + 32 * wr + 16 * sr + 4 * (ln >> 4) + r;
                float v = fmaxf(acc[sr][sc][r] + bv, 0.f);
                const unsigned short h = bf16rne(v);
                oh[(size_t)R * 512 + C] = h;
                ol[(size_t)R * 512 + C] = bf16rne(v - bf16f(h));
            }
    }
}

// ---------------------------------------------------------------------------
// K1: hidden GEMM (fused conversion). 256 blocks: [0,128) MLP1, [128,256) MLPg.
// Blocks 0..31 (short mlp0 blocks) additionally compute colmean stripes.
__global__ __launch_bounds__(256) void k1_hidden(
    const float* __restrict__ H, const float* __restrict__ P, const float* __restrict__ G,
    const float* __restrict__ W1, const float* __restrict__ b1,
    const float* __restrict__ W1g, const float* __restrict__ b1g,
    char* __restrict__ wsb)
{
    __shared__ unsigned short sAh[2][4096], sAl[2][4096], sW[2][4096];
    const int bx = blockIdx.x, t = threadIdx.x;
    if (bx == 0 && t == 0) {
        *(unsigned*)(wsb + B_CTR) = 0u;
        *(unsigned long long*)(wsb + B_TOT) = 0ull;
    }
    const int mlp = bx >> 7, bi = bx & 127;
    const int m0 = (bi >> 3) * 64, n0 = (bi & 7) * 64;
    const int wv = t >> 6, ln = t & 63;

    if (mlp)
        hidden_body<8>(H, P, W1g, b1g,
                       (unsigned short*)(wsb + B_HGH), (unsigned short*)(wsb + B_HGL),
                       sAh, sAl, sW, m0, n0, wv, ln);
    else
        hidden_body<4>(H, P, W1, b1,
                       (unsigned short*)(wsb + B_H1H), (unsigned short*)(wsb + B_H1L),
                       sAh, sAl, sW, m0, n0, wv, ln);

    if (bx < 32) {   // colmean raw partials: 64 rows of P (bx<16) or G, col t
        const int cb = bx;
        const float* M = (cb & 16) ? G : P;
        const float* p = M + (size_t)(cb & 15) * 64 * DX + t;
        float s0 = 0.f, s1 = 0.f, s2 = 0.f, s3 = 0.f;
        #pragma unroll 4
        for (int r = 0; r < 64; r += 4) {
            s0 += p[(r + 0) * DX]; s1 += p[(r + 1) * DX];
            s2 += p[(r + 2) * DX]; s3 += p[(r + 3) * DX];
        }
        ((float*)(wsb + B_CM))[((cb >> 4) * 16 + (cb & 15)) * 256 + t] = (s0 + s1) + (s2 + s3);
    }
}

// ---------------------------------------------------------------------------
// K2: mu = Hid @ W2 (b2 contributes exactly 0 against centered Y) dotted with
// (Y - colmean(Y)) on the fly. Hid staged via global_load_lds (already bf16);
// W2 reg-converted in-pipeline. Fence-free fixed-point atomic finish (R9).
// 256 blocks: bx = [mlp:1][ksplit:1][rowtile:4][coltile:2]; tile 64x64.
__global__ __launch_bounds__(256) void k2_out(
    const float* __restrict__ P, const float* __restrict__ G,
    const float* __restrict__ W2, const float* __restrict__ W2g,
    char* __restrict__ wsb, float* __restrict__ out)
{
    __shared__ unsigned short sAh[2][4096], sAl[2][4096], sW[2][4096];
    __shared__ float red[256];
    const int bx = blockIdx.x, t = threadIdx.x;
    const int mlp = bx >> 7;
    const int ks  = (bx >> 6) & 1;
    const int m0  = ((bx >> 2) & 15) * 64;
    const int n0  = (bx & 3) * 64;
    const int wv = t >> 6, ln = t & 63;
    const int wr = wv >> 1, wc = wv & 1;

    const unsigned short* ha = (const unsigned short*)(wsb + (mlp ? B_HGH : B_H1H));
    const unsigned short* la = (const unsigned short*)(wsb + (mlp ? B_HGL : B_H1L));
    const float* wt = mlp ? W2g : W2;    // fp32 [512][256]
    const float* Y  = mlp ? G : P;
    const float* cm = (const float*)(wsb + B_CM) + mlp * 4096;
    const int kb = ks * 256;

    float wR[2][16];
    auto loadW = [&](int rb, int c) {
        #pragma unroll
        for (int j = 0; j < 16; ++j)
            wR[rb][j] = wt[(size_t)(kb + c * 64 + wv * 16 + j) * DX + n0 + ln];
    };
    auto writeW = [&](int rb, int b) {
        #pragma unroll
        for (int s = 0; s < 2; ++s) {
            const int byo = ln * 128 + ((((2 * wv + s) ^ (ln & 7))) << 4);
            *(ushort4*)((char*)sW[b] + byo) =
                make_ushort4(bf16rne(wR[rb][s*8+0]), bf16rne(wR[rb][s*8+1]),
                             bf16rne(wR[rb][s*8+2]), bf16rne(wR[rb][s*8+3]));
            *(ushort4*)((char*)sW[b] + byo + 8) =
                make_ushort4(bf16rne(wR[rb][s*8+4]), bf16rne(wR[rb][s*8+5]),
                             bf16rne(wR[rb][s*8+6]), bf16rne(wR[rb][s*8+7]));
        }
    };

    stage_bf16(ha, m0, kb, 512, sAh[0], wv, ln);
    stage_bf16(la, m0, kb, 512, sAl[0], wv, ln);
    loadW(0, 0);
    writeW(0, 0);
    asm volatile("s_waitcnt vmcnt(0)" ::: "memory");
    __syncthreads();

    f32x4 zero = {0.f, 0.f, 0.f, 0.f};
    f32x4 acc[2][2] = {{zero, zero}, {zero, zero}};

    #pragma unroll
    for (int c = 0; c < 4; ++c) {
        const int b = c & 1;
        if (c + 1 < 4) {
            stage_bf16(ha, m0, kb + (c + 1) * 64, 512, sAh[1 - b], wv, ln);
            stage_bf16(la, m0, kb + (c + 1) * 64, 512, sAl[1 - b], wv, ln);
            loadW(1 - b, c + 1);
        }
        #pragma unroll
        for (int kc = 0; kc < 64; kc += 32) {
            uint4 fh[2], fl[2], fw[2];
            #pragma unroll
            for (int s = 0; s < 2; ++s) {
                const int ra = 32 * wr + 16 * s + (ln & 15);
                fh[s] = ldsfrag(sAh[b], ra, kc, ln);
                fl[s] = ldsfrag(sAl[b], ra, kc, ln);
                fw[s] = ldsfrag(sW[b], 32 * wc + 16 * s + (ln & 15), kc, ln);
            }
            #pragma unroll
            for (int sr = 0; sr < 2; ++sr)
                #pragma unroll
                for (int sc = 0; sc < 2; ++sc) {
                    acc[sr][sc] = MFMA(fh[sr], fw[sc], acc[sr][sc]);
                    acc[sr][sc] = MFMA(fl[sr], fw[sc], acc[sr][sc]);
                }
        }
        if (c + 1 < 4) writeW(1 - b, 1 - b);
        asm volatile("s_waitcnt vmcnt(0)" ::: "memory");
        __syncthreads();
    }

    float part = 0.f;
    #pragma unroll
    for (int sc = 0; sc < 2; ++sc) {
        const int C = n0 + 32 * wc + 16 * sc + (ln & 15);
        float s = 0.f;
        #pragma unroll
        for (int st = 0; st < 16; ++st) s += cm[st * 256 + C];
        const float e = s * (1.0f / NR);
        #pragma unroll
        for (int sr = 0; sr < 2; ++sr)
            #pragma unroll
            for (int r = 0; r < 4; ++r) {
                const int R = m0 + 32 * wr + 16 * sr + 4 * (ln >> 4) + r;
                part += acc[sr][sc][r] * (Y[(size_t)R * DX + C] - e);
            }
    }
    red[t] = part;
    __syncthreads();
    #pragma unroll
    for (int sft = 128; sft > 0; sft >>= 1) {
        if (t < sft) red[t] += red[t + sft];
        __syncthreads();
    }

    if (t == 0) {
        unsigned long long* tot = (unsigned long long*)(wsb + B_TOT);
        unsigned* ctr = (unsigned*)(wsb + B_CTR);
        const long long ll = llrint((double)red[0] * FIXSCALE);
        atomicAdd(tot, (unsigned long long)ll);
        asm volatile("s_waitcnt vmcnt(0)" ::: "memory");  // total-add ack before ctr-add
        const unsigned prev = atomicAdd(ctr, 1u);
        if (prev == 255u) {
            const unsigned long long s = atomicAdd(tot, 0ull);  // coherent read
            out[0] = (float)((double)(long long)s * (1.0 / FIXSCALE) * (1.0 / NR));
        }
    }
}

// ---------------------------------------------------------------------------
extern "C" void kernel_launch(void* const* d_in, const int* in_sizes, int n_in,
                              void* d_out, int out_size, void* d_ws, size_t ws_size,
                              hipStream_t stream)
{
    const float* H   = (const float*)d_in[0];
    const float* P   = (const float*)d_in[1];
    const float* G   = (const float*)d_in[2];
    const float* W1  = (const float*)d_in[3];
    const float* b1  = (const float*)d_in[4];
    const float* W2  = (const float*)d_in[5];
    // d_in[6] = b2: provably zero contribution
    const float* W1g = (const float*)d_in[7];
    const float* b1g = (const float*)d_in[8];
    const float* W2g = (const float*)d_in[9];
    // d_in[10] = b2g: unused
    char* wsb = (char*)d_ws;
    float* out = (float*)d_out;

    hipLaunchKernelGGL(k1_hidden, dim3(256), dim3(256), 0, stream,
                       H, P, G, W1, b1, W1g, b1g, wsb);
    hipLaunchKernelGGL(k2_out,    dim3(256), dim3(256), 0, stream,
                       P, G, W2, W2g, wsb, out);
}